// Round 12
// baseline (416.062 us; speedup 1.0000x reference)
//
#include <hip/hip_runtime.h>
#include <hip/hip_fp16.h>
#include <math.h>

#define BATCH 16
#define CH 3
#define CKCH 6
#define HH 256
#define WW 256
#define NSTEPS 10
#define SW 132                  // half-spectrum row stride (__half2 units), 129 used
#define HSP (HH*SW)
#define NUNITS 1536             // 48 planes x 32 strips
#define XN4 786432              // BATCH*CH*HH*WW/4
#define IDX(i) ((i) ^ (((i) >> 4) & 15))

struct __align__(8) h4 { __half2 a, b; };

__device__ __forceinline__ float2 cmulf(float2 a, float2 b) {
  return make_float2(a.x * b.x - a.y * b.y, a.x * b.y + a.y * b.x);
}
__device__ __forceinline__ float4 h4tof4(h4 v) {
  float2 f0 = __half22float2(v.a), f1 = __half22float2(v.b);
  return make_float4(f0.x, f0.y, f1.x, f1.y);
}
__device__ __forceinline__ h4 f4toh4(float4 v) {
  h4 r;
  r.a = __float22half2_rn(make_float2(v.x, v.y));
  r.b = __float22half2_rn(make_float2(v.z, v.w));
  return r;
}

struct SmBig {
  __half su[12][264];
  __half sdm[2][10][264];
  float2 zz[4][256];
};

// fused radix-2^2 Stockham FFT-256, one wave, IN-PLACE (swizzled via IDX).
template <int INV>
__device__ __forceinline__ void wave_fft256(float2* buf, const float2* tw, int l) {
#pragma unroll
  for (int st = 0; st < 4; ++st) {
    int m = 1 << (2 * st);
    int r = l & (m - 1);
    int qm = l - r;
    float2 w1 = tw[qm], w2 = tw[qm + 64], w3 = tw[2 * qm];
    if (INV) { w1.y = -w1.y; w2.y = -w2.y; w3.y = -w3.y; }
    float2 x0 = buf[IDX(l)];
    float2 x1 = buf[IDX(l + 128)];
    float2 x2 = buf[IDX(l + 64)];
    float2 x3 = buf[IDX(l + 192)];
    __builtin_amdgcn_wave_barrier();
    float2 aA = make_float2(x0.x + x1.x, x0.y + x1.y);
    float2 bA = cmulf(w1, make_float2(x0.x - x1.x, x0.y - x1.y));
    float2 aB = make_float2(x2.x + x3.x, x2.y + x3.y);
    float2 bB = cmulf(w2, make_float2(x2.x - x3.x, x2.y - x3.y));
    int base = 4 * qm + r;
    buf[IDX(base)]         = make_float2(aA.x + aB.x, aA.y + aB.y);
    buf[IDX(base + 2 * m)] = cmulf(w3, make_float2(aA.x - aB.x, aA.y - aB.y));
    buf[IDX(base + m)]     = make_float2(bA.x + bB.x, bA.y + bB.y);
    buf[IDX(base + 3 * m)] = cmulf(w3, make_float2(bA.x - bB.x, bA.y - bB.y));
    __builtin_amdgcn_wave_barrier();
  }
}

// ---------------- init: x->fp16 cast + HinvT build ----------------
__global__ __launch_bounds__(256, 4) void fb_init(const float4* __restrict__ x4,
                                                  __half* __restrict__ xh,
                                                  const float* __restrict__ kerK,
                                                  const float* __restrict__ rho,
                                                  float* __restrict__ HinvT) {
  __shared__ float ctab[256], kerH[25];
  int tid = threadIdx.x;
  for (int idx = blockIdx.x * 256 + tid; idx < XN4; idx += gridDim.x * 256)
    ((h4*)xh)[idx] = f4toh4(x4[idx]);
  ctab[tid] = cosf(6.283185307179586f * (float)tid / 256.0f);
  __syncthreads();
  for (int unit = blockIdx.x; unit < 30 * 129; unit += gridDim.x) {
    int kx = unit % 129, ic = unit / 129;
    int c = ic % CH, i = ic / CH;
    if (tid < 25) {
      int a = tid / 5, b2 = tid % 5;
      float s = (a == 2 && b2 == 2) ? 1.0f : 0.0f;
      for (int o = 0; o < 2; ++o) {
        int ck = c * 2 + o;
        const float* Kk = kerK + (i * CKCH + ck) * 9;
        float rh = rho[i * CKCH + ck];
        float ac = 0.f;
        for (int ty = 0; ty < 3; ++ty)
          for (int tx = 0; tx < 3; ++tx) {
            int ya2 = a - 2 + ty, xb = b2 - 2 + tx;
            if (ya2 >= 0 && ya2 < 3 && xb >= 0 && xb < 3)
              ac += Kk[ya2 * 3 + xb] * Kk[ty * 3 + tx];
          }
        s += rh * ac;
      }
      kerH[tid] = s;
    }
    __syncthreads();
    float acc = 0.f;
#pragma unroll
    for (int a = 0; a < 5; ++a)
#pragma unroll
      for (int b2 = 0; b2 < 5; ++b2)
        acc += kerH[a * 5 + b2] * ctab[(tid * (a - 2) + kx * (b2 - 2)) & 255];
    HinvT[((size_t)ic * 129 + kx) * 256 + tid] = 1.0f / (65536.0f * acc);
    __syncthreads();
  }
}

// ---------------- bigstep (R10 structure + isolated change: mu prefetch) ----------------
__global__ __launch_bounds__(256, 6) void fb_bigstep(
    int step, const __half* __restrict__ xh, const float* __restrict__ kerK,
    const float* __restrict__ beta, const float* __restrict__ rho,
    const __half2* __restrict__ specIn, const __half* __restrict__ muIn,
    __half* __restrict__ muOut, __half2* __restrict__ specOut) {
  __shared__ SmBig S;
  __shared__ float2 tw[128];
  int tid = threadIdx.x;
  if (tid < 128) {
    float sn, cs;
    sincosf(-6.283185307179586f * (float)tid / 256.0f, &sn, &cs);
    tw[tid] = make_float2(cs, sn);
  }
  int unit = blockIdx.x;
  int strip = unit & 31;
  int bc = unit >> 5;
  int c = bc % CH, b = bc / CH;
  int y0 = strip * 8;
  int u = tid >> 6, l = tid & 63;
  bool first = (step == 0);
  float2* Z = &S.zz[u][0];
  __syncthreads();

  // phase 1: packed inverse row FFTs of prev spectra -> su
  if (!first) {
    for (int round = 0; round < 2; ++round) {
      int j = round * 4 + u;
      bool act = (j < 6);
      int ya = y0 - 2 + 2 * j;
      if (act && ya >= 0 && ya < HH) {
        const __half2* Ar = specIn + ((size_t)bc * HH + ya) * SW;
        const __half2* Br = Ar + SW;
#pragma unroll
        for (int h = 0; h < 2; ++h) {
          int t = l + h * 64;
          float2 A = __half22float2(Ar[t]), B = __half22float2(Br[t]);
          Z[IDX(t)] = make_float2(A.x - B.y, A.y + B.x);
          int mI = 128 - t;
          float2 Am = __half22float2(Ar[mI]), Bm = __half22float2(Br[mI]);
          float2 zh;
          if (t == 0) zh = make_float2(Am.x - Bm.y, Am.y + Bm.x);
          else        zh = make_float2(Am.x + Bm.y, Bm.x - Am.y);
          Z[IDX(t + 128)] = zh;
        }
        __builtin_amdgcn_wave_barrier();
        wave_fft256<1>(Z, tw, l);
        int r0 = 2 * j;
#pragma unroll
        for (int h = 0; h < 4; ++h) {
          int xx = l + h * 64;
          float2 z = Z[IDX(xx)];
          S.su[r0][4 + xx] = __float2half(z.x);
          S.su[r0 + 1][4 + xx] = __float2half(z.y);
        }
      } else if (act) {
        int r0 = 2 * j;
        for (int k2 = l; k2 < 264; k2 += 64) {
          S.su[r0][k2] = __float2half(0.f);
          S.su[r0 + 1][k2] = __float2half(0.f);
        }
      }
    }
    __syncthreads();

    // phase 2: prefetch all 5 mu loads (overlapped), then conv + shrink + mu update
    bool muZero = (step == 1);
    int ps = step - 1;
    h4 mpre[5];
    if (!muZero) {
#pragma unroll
      for (int it = 0; it < 5; ++it) {
        int task = it * 4 + u;
        int o = task / 10, rr = task % 10;
        int y = y0 - 1 + rr;
        int ck = c * 2 + o;
        if (y >= 0 && y < HH) {
          size_t gidx = (((size_t)b * CKCH + ck) * HH + y) * WW + 4 * l;
          mpre[it] = *(const h4*)(muIn + gidx);
        }
      }
    }
#pragma unroll 1
    for (int it = 0; it < 5; ++it) {
      int task = it * 4 + u;
      int o = task / 10, rr = task % 10;
      int y = y0 - 1 + rr;
      int ck = c * 2 + o;
      float4 dq = make_float4(0.f, 0.f, 0.f, 0.f);
      if (y >= 0 && y < HH) {
        const float* Kp = kerK + (ps * CKCH + ck) * 9;
        float kk[9];
#pragma unroll
        for (int q = 0; q < 9; ++q) kk[q] = Kp[q];
        float gm = beta[ps * CKCH + ck] / rho[ps * CKCH + ck];
        float4 c4 = make_float4(0.f, 0.f, 0.f, 0.f);
#pragma unroll
        for (int dy = 0; dy < 3; ++dy) {
          float4 mid = h4tof4(*(const h4*)&S.su[rr + dy][4 + 4 * l]);
          float lft = __shfl_up(mid.w, 1); if (l == 0) lft = 0.f;
          float rgt = __shfl_down(mid.x, 1); if (l == 63) rgt = 0.f;
          float w0 = kk[dy * 3], w1 = kk[dy * 3 + 1], w2 = kk[dy * 3 + 2];
          c4.x += w0 * lft   + w1 * mid.x + w2 * mid.y;
          c4.y += w0 * mid.x + w1 * mid.y + w2 * mid.z;
          c4.z += w0 * mid.y + w1 * mid.z + w2 * mid.w;
          c4.w += w0 * mid.z + w1 * mid.w + w2 * rgt;
        }
        size_t gidx = (((size_t)b * CKCH + ck) * HH + y) * WW + 4 * l;
        float4 m4 = muZero ? make_float4(0.f, 0.f, 0.f, 0.f) : h4tof4(mpre[it]);
        float4 mn4;
        {
          float v = c4.x + m4.x, av = fabsf(v) - gm;
          float pn = (av > 0.f) ? ((v > 0.f) ? av : -av) : 0.f;
          mn4.x = m4.x + c4.x - pn; dq.x = pn - mn4.x;
        }
        {
          float v = c4.y + m4.y, av = fabsf(v) - gm;
          float pn = (av > 0.f) ? ((v > 0.f) ? av : -av) : 0.f;
          mn4.y = m4.y + c4.y - pn; dq.y = pn - mn4.y;
        }
        {
          float v = c4.z + m4.z, av = fabsf(v) - gm;
          float pn = (av > 0.f) ? ((v > 0.f) ? av : -av) : 0.f;
          mn4.z = m4.z + c4.z - pn; dq.z = pn - mn4.z;
        }
        {
          float v = c4.w + m4.w, av = fabsf(v) - gm;
          float pn = (av > 0.f) ? ((v > 0.f) ? av : -av) : 0.f;
          mn4.w = m4.w + c4.w - pn; dq.w = pn - mn4.w;
        }
        if (rr >= 1 && rr <= 8) *(h4*)(muOut + gidx) = f4toh4(mn4);
      }
      *(h4*)&S.sdm[o][rr][4 + 4 * l] = f4toh4(dq);
    }
  }
  __syncthreads();

  // phase 3: w1 = f + sum_o conv(rho*flipK, d); packed forward row FFT
  int ya = y0 + 2 * u;
  const h4* xa = (const h4*)(xh + ((size_t)(b * CH + c) * HH + ya) * WW);
  float4 va = h4tof4(xa[l]), vb = h4tof4(xa[64 + l]);
  if (!first) {
#pragma unroll
    for (int o = 0; o < 2; ++o) {
      int ck = c * 2 + o;
      float rh = rho[step * CKCH + ck];
      const float* Kk = kerK + (step * CKCH + ck) * 9;
      float kw[9];
#pragma unroll
      for (int dy = 0; dy < 3; ++dy)
#pragma unroll
        for (int dx = 0; dx < 3; ++dx)
          kw[dy * 3 + dx] = rh * Kk[(2 - dy) * 3 + (2 - dx)];
      float4 mid[4]; float lf[4], rg[4];
#pragma unroll
      for (int r4 = 0; r4 < 4; ++r4) {
        mid[r4] = h4tof4(*(const h4*)&S.sdm[o][2 * u + r4][4 + 4 * l]);
        lf[r4] = __shfl_up(mid[r4].w, 1); if (l == 0) lf[r4] = 0.f;
        rg[r4] = __shfl_down(mid[r4].x, 1); if (l == 63) rg[r4] = 0.f;
      }
#pragma unroll
      for (int dy = 0; dy < 3; ++dy) {
        float w0 = kw[dy * 3], w1 = kw[dy * 3 + 1], w2 = kw[dy * 3 + 2];
        va.x += w0 * lf[dy]     + w1 * mid[dy].x   + w2 * mid[dy].y;
        va.y += w0 * mid[dy].x  + w1 * mid[dy].y   + w2 * mid[dy].z;
        va.z += w0 * mid[dy].y  + w1 * mid[dy].z   + w2 * mid[dy].w;
        va.w += w0 * mid[dy].z  + w1 * mid[dy].w   + w2 * rg[dy];
        vb.x += w0 * lf[dy+1]    + w1 * mid[dy+1].x + w2 * mid[dy+1].y;
        vb.y += w0 * mid[dy+1].x + w1 * mid[dy+1].y + w2 * mid[dy+1].z;
        vb.z += w0 * mid[dy+1].y + w1 * mid[dy+1].z + w2 * mid[dy+1].w;
        vb.w += w0 * mid[dy+1].z + w1 * mid[dy+1].w + w2 * rg[dy+1];
      }
    }
  }
  Z[IDX(4 * l + 0)] = make_float2(va.x, vb.x);
  Z[IDX(4 * l + 1)] = make_float2(va.y, vb.y);
  Z[IDX(4 * l + 2)] = make_float2(va.z, vb.z);
  Z[IDX(4 * l + 3)] = make_float2(va.w, vb.w);
  __builtin_amdgcn_wave_barrier();
  wave_fft256<0>(Z, tw, l);
  __half2* Sa = specOut + ((size_t)bc * HH + ya) * SW;
  __half2* Sb = Sa + SW;
#pragma unroll
  for (int h = 0; h < 2; ++h) {
    int k = l + h * 64;
    int mI = (256 - k) & 255;
    float2 zk = Z[IDX(k)], zm = Z[IDX(mI)];
    Sa[k] = __float22half2_rn(make_float2(0.5f * (zk.x + zm.x), 0.5f * (zk.y - zm.y)));
    Sb[k] = __float22half2_rn(make_float2(0.5f * (zk.y + zm.y), 0.5f * (zm.x - zk.x)));
  }
  if (l == 0) {
    float2 z1 = Z[IDX(128)];
    Sa[128] = __float22half2_rn(make_float2(z1.x, 0.f));
    Sb[128] = __float22half2_rn(make_float2(z1.y, 0.f));
  }
}

// ------- colfft: coalesced 8-col tiles, 512 threads, 1 col/wave, group 0 takes kx=128 -------
__global__ __launch_bounds__(512) void fb_colfft(int step, __half2* __restrict__ spec,
                                                 const float* __restrict__ HinvT) {
  int g = blockIdx.x & 15;        // col group: kx 8g..8g+7
  int bc = blockIdx.x >> 4;       // plane (48)
  int c = bc % CH;
  int x0 = g * 8;
  __half2* f = spec + (size_t)bc * HSP;

  __shared__ float2 az[9][257];   // 8 cols (+ kx=128 for g==0); pad 257
  __shared__ float2 tw[128];
  int tid = threadIdx.x;
  if (tid < 128) {
    float sn, cs;
    sincosf(-6.283185307179586f * (float)tid / 256.0f, &sn, &cs);
    tw[tid] = make_float2(cs, sn);
  }
  int col8 = tid & 7;
  int rowq = tid >> 3;            // 0..63
#pragma unroll
  for (int rb = 0; rb < 4; ++rb) {
    int row = rb * 64 + rowq;
    az[col8][IDX(row)] = __half22float2(f[row * SW + x0 + col8]);
  }
  if (g == 0 && tid < 256) az[8][IDX(tid)] = __half22float2(f[tid * SW + 128]);
  __syncthreads();

  int u = tid >> 6, l = tid & 63;
  {
    int kx = x0 + u;
    float2* A = &az[u][0];
    wave_fft256<0>(A, tw, l);
    const float* T = HinvT + ((size_t)(step * CH + c) * 129 + kx) * 256;
#pragma unroll
    for (int h = 0; h < 4; ++h) {
      int idx = l + 64 * h;
      float tv = T[idx];
      float2 z = A[IDX(idx)];
      A[IDX(idx)] = make_float2(z.x * tv, z.y * tv);
    }
    __builtin_amdgcn_wave_barrier();
    wave_fft256<1>(A, tw, l);
  }
  if (g == 0 && u == 0) {         // kx = 128 handled by wave 0
    float2* A = &az[8][0];
    wave_fft256<0>(A, tw, l);
    const float* T = HinvT + ((size_t)(step * CH + c) * 129 + 128) * 256;
#pragma unroll
    for (int h = 0; h < 4; ++h) {
      int idx = l + 64 * h;
      float tv = T[idx];
      float2 z = A[IDX(idx)];
      A[IDX(idx)] = make_float2(z.x * tv, z.y * tv);
    }
    __builtin_amdgcn_wave_barrier();
    wave_fft256<1>(A, tw, l);
  }
  __syncthreads();

#pragma unroll
  for (int rb = 0; rb < 4; ++rb) {
    int row = rb * 64 + rowq;
    f[row * SW + x0 + col8] = __float22half2_rn(az[col8][IDX(row)]);
  }
  if (g == 0 && tid < 256) f[tid * SW + 128] = __float22half2_rn(az[8][IDX(tid)]);
}

// ---------------- final inverse row FFT -> out (fp32) ----------------
__global__ __launch_bounds__(256, 6) void fb_final(const __half2* __restrict__ spec,
                                                   float* __restrict__ out) {
  __shared__ SmBig S;
  __shared__ float2 tw[128];
  int tid = threadIdx.x;
  if (tid < 128) {
    float sn, cs;
    sincosf(-6.283185307179586f * (float)tid / 256.0f, &sn, &cs);
    tw[tid] = make_float2(cs, sn);
  }
  __syncthreads();
  int unit = blockIdx.x;
  int strip = unit & 31;
  int bc = unit >> 5;
  int y0 = strip * 8;
  int u = tid >> 6, l = tid & 63;
  float2* Z = &S.zz[u][0];
  int ya = y0 + 2 * u;
  const __half2* Ar = spec + ((size_t)bc * HH + ya) * SW;
  const __half2* Br = Ar + SW;
#pragma unroll
  for (int h = 0; h < 2; ++h) {
    int t = l + h * 64;
    float2 A = __half22float2(Ar[t]), B = __half22float2(Br[t]);
    Z[IDX(t)] = make_float2(A.x - B.y, A.y + B.x);
    int mI = 128 - t;
    float2 Am = __half22float2(Ar[mI]), Bm = __half22float2(Br[mI]);
    float2 zh;
    if (t == 0) zh = make_float2(Am.x - Bm.y, Am.y + Bm.x);
    else        zh = make_float2(Am.x + Bm.y, Bm.x - Am.y);
    Z[IDX(t + 128)] = zh;
  }
  __builtin_amdgcn_wave_barrier();
  wave_fft256<1>(Z, tw, l);
  float* oa = out + ((size_t)bc * HH + ya) * WW;
#pragma unroll
  for (int h = 0; h < 4; ++h) {
    int xx = l + h * 64;
    float2 z = Z[IDX(xx)];
    oa[xx] = z.x;
    oa[WW + xx] = z.y;
  }
}

extern "C" void kernel_launch(void* const* d_in, const int* in_sizes, int n_in,
                              void* d_out, int out_size, void* d_ws, size_t ws_size,
                              hipStream_t stream) {
  const float4* x4 = (const float4*)d_in[0];
  const float* kerK = (const float*)d_in[1];
  const float* beta = (const float*)d_in[2];
  const float* rho = (const float*)d_in[3];
  float* out = (float*)d_out;

  const size_t PMU = (size_t)BATCH * CKCH * HH * WW;   // 6291456
  const size_t SPL = (size_t)BATCH * CH * HSP;         // 1622016 __half2

  __half* muA = (__half*)d_ws;
  __half* muB = muA + PMU;
  __half2* specA = (__half2*)(muB + PMU);
  __half2* specB = specA + SPL;
  float* HinvT = (float*)(specB + SPL);
  __half* xh = (__half*)(HinvT + (size_t)30 * 129 * 256);

  fb_init<<<NUNITS, 256, 0, stream>>>(x4, xh, kerK, rho, HinvT);
  for (int i = 0; i < NSTEPS; ++i) {
    __half2* sIn = (i & 1) ? specA : specB;
    __half2* sOut = (i & 1) ? specB : specA;
    const __half* mi = (i & 1) ? muB : muA;
    __half* mo = (i & 1) ? muA : muB;
    fb_bigstep<<<NUNITS, 256, 0, stream>>>(i, xh, kerK, beta, rho, sIn, mi, mo, sOut);
    fb_colfft<<<48 * 16, 512, 0, stream>>>(i, sOut, HinvT);
  }
  fb_final<<<NUNITS, 256, 0, stream>>>(specB, out);
}

// Round 13
// 395.668 us; speedup vs baseline: 1.0515x; 1.0515x over previous
//
#include <hip/hip_runtime.h>
#include <hip/hip_fp16.h>
#include <math.h>

#define BATCH 16
#define CH 3
#define CKCH 6
#define HH 256
#define WW 256
#define NSTEPS 10
#define SW 132                  // half-spectrum row stride (__half2 units), 129 used
#define HSP (HH*SW)
#define NUNITS 1536             // 48 planes x 32 strips
#define XN4 786432              // BATCH*CH*HH*WW/4
#define IDX(i) ((i) ^ (((i) >> 4) & 15))

struct __align__(8) h4 { __half2 a, b; };

__device__ __forceinline__ float2 cmulf(float2 a, float2 b) {
  return make_float2(a.x * b.x - a.y * b.y, a.x * b.y + a.y * b.x);
}
__device__ __forceinline__ float4 h4tof4(h4 v) {
  float2 f0 = __half22float2(v.a), f1 = __half22float2(v.b);
  return make_float4(f0.x, f0.y, f1.x, f1.y);
}
__device__ __forceinline__ h4 f4toh4(float4 v) {
  h4 r;
  r.a = __float22half2_rn(make_float2(v.x, v.y));
  r.b = __float22half2_rn(make_float2(v.z, v.w));
  return r;
}

struct SmBig {
  __half su[12][264];
  __half sdm[2][10][264];
  float2 zz[4][256];
};

// fused radix-2^2 Stockham FFT-256, one wave, IN-PLACE (swizzled via IDX).
template <int INV>
__device__ __forceinline__ void wave_fft256(float2* buf, const float2* tw, int l) {
#pragma unroll
  for (int st = 0; st < 4; ++st) {
    int m = 1 << (2 * st);
    int r = l & (m - 1);
    int qm = l - r;
    float2 w1 = tw[qm], w2 = tw[qm + 64], w3 = tw[2 * qm];
    if (INV) { w1.y = -w1.y; w2.y = -w2.y; w3.y = -w3.y; }
    float2 x0 = buf[IDX(l)];
    float2 x1 = buf[IDX(l + 128)];
    float2 x2 = buf[IDX(l + 64)];
    float2 x3 = buf[IDX(l + 192)];
    __builtin_amdgcn_wave_barrier();
    float2 aA = make_float2(x0.x + x1.x, x0.y + x1.y);
    float2 bA = cmulf(w1, make_float2(x0.x - x1.x, x0.y - x1.y));
    float2 aB = make_float2(x2.x + x3.x, x2.y + x3.y);
    float2 bB = cmulf(w2, make_float2(x2.x - x3.x, x2.y - x3.y));
    int base = 4 * qm + r;
    buf[IDX(base)]         = make_float2(aA.x + aB.x, aA.y + aB.y);
    buf[IDX(base + 2 * m)] = cmulf(w3, make_float2(aA.x - aB.x, aA.y - aB.y));
    buf[IDX(base + m)]     = make_float2(bA.x + bB.x, bA.y + bB.y);
    buf[IDX(base + 3 * m)] = cmulf(w3, make_float2(bA.x - bB.x, bA.y - bB.y));
    __builtin_amdgcn_wave_barrier();
  }
}

// ---------------- init: x->fp16 cast + HinvT build ----------------
__global__ __launch_bounds__(256, 4) void fb_init(const float4* __restrict__ x4,
                                                  __half* __restrict__ xh,
                                                  const float* __restrict__ kerK,
                                                  const float* __restrict__ rho,
                                                  float* __restrict__ HinvT) {
  __shared__ float ctab[256], kerH[25];
  int tid = threadIdx.x;
  for (int idx = blockIdx.x * 256 + tid; idx < XN4; idx += gridDim.x * 256)
    ((h4*)xh)[idx] = f4toh4(x4[idx]);
  ctab[tid] = cosf(6.283185307179586f * (float)tid / 256.0f);
  __syncthreads();
  for (int unit = blockIdx.x; unit < 30 * 129; unit += gridDim.x) {
    int kx = unit % 129, ic = unit / 129;
    int c = ic % CH, i = ic / CH;
    if (tid < 25) {
      int a = tid / 5, b2 = tid % 5;
      float s = (a == 2 && b2 == 2) ? 1.0f : 0.0f;
      for (int o = 0; o < 2; ++o) {
        int ck = c * 2 + o;
        const float* Kk = kerK + (i * CKCH + ck) * 9;
        float rh = rho[i * CKCH + ck];
        float ac = 0.f;
        for (int ty = 0; ty < 3; ++ty)
          for (int tx = 0; tx < 3; ++tx) {
            int ya2 = a - 2 + ty, xb = b2 - 2 + tx;
            if (ya2 >= 0 && ya2 < 3 && xb >= 0 && xb < 3)
              ac += Kk[ya2 * 3 + xb] * Kk[ty * 3 + tx];
          }
        s += rh * ac;
      }
      kerH[tid] = s;
    }
    __syncthreads();
    float acc = 0.f;
#pragma unroll
    for (int a = 0; a < 5; ++a)
#pragma unroll
      for (int b2 = 0; b2 < 5; ++b2)
        acc += kerH[a * 5 + b2] * ctab[(tid * (a - 2) + kx * (b2 - 2)) & 255];
    HinvT[((size_t)ic * 129 + kx) * 256 + tid] = 1.0f / (65536.0f * acc);
    __syncthreads();
  }
}

// ---------------- bigstep (proven R10 structure, no prefetch) ----------------
__global__ __launch_bounds__(256, 6) void fb_bigstep(
    int step, const __half* __restrict__ xh, const float* __restrict__ kerK,
    const float* __restrict__ beta, const float* __restrict__ rho,
    const __half2* __restrict__ specIn, const __half* __restrict__ muIn,
    __half* __restrict__ muOut, __half2* __restrict__ specOut) {
  __shared__ SmBig S;
  __shared__ float2 tw[128];
  int tid = threadIdx.x;
  if (tid < 128) {
    float sn, cs;
    sincosf(-6.283185307179586f * (float)tid / 256.0f, &sn, &cs);
    tw[tid] = make_float2(cs, sn);
  }
  int unit = blockIdx.x;
  int strip = unit & 31;
  int bc = unit >> 5;
  int c = bc % CH, b = bc / CH;
  int y0 = strip * 8;
  int u = tid >> 6, l = tid & 63;
  bool first = (step == 0);
  float2* Z = &S.zz[u][0];
  __syncthreads();

  // phase 1: packed inverse row FFTs of prev spectra -> su
  if (!first) {
    for (int round = 0; round < 2; ++round) {
      int j = round * 4 + u;
      bool act = (j < 6);
      int ya = y0 - 2 + 2 * j;
      if (act && ya >= 0 && ya < HH) {
        const __half2* Ar = specIn + ((size_t)bc * HH + ya) * SW;
        const __half2* Br = Ar + SW;
#pragma unroll
        for (int h = 0; h < 2; ++h) {
          int t = l + h * 64;
          float2 A = __half22float2(Ar[t]), B = __half22float2(Br[t]);
          Z[IDX(t)] = make_float2(A.x - B.y, A.y + B.x);
          int mI = 128 - t;
          float2 Am = __half22float2(Ar[mI]), Bm = __half22float2(Br[mI]);
          float2 zh;
          if (t == 0) zh = make_float2(Am.x - Bm.y, Am.y + Bm.x);
          else        zh = make_float2(Am.x + Bm.y, Bm.x - Am.y);
          Z[IDX(t + 128)] = zh;
        }
        __builtin_amdgcn_wave_barrier();
        wave_fft256<1>(Z, tw, l);
        int r0 = 2 * j;
#pragma unroll
        for (int h = 0; h < 4; ++h) {
          int xx = l + h * 64;
          float2 z = Z[IDX(xx)];
          S.su[r0][4 + xx] = __float2half(z.x);
          S.su[r0 + 1][4 + xx] = __float2half(z.y);
        }
      } else if (act) {
        int r0 = 2 * j;
        for (int k2 = l; k2 < 264; k2 += 64) {
          S.su[r0][k2] = __float2half(0.f);
          S.su[r0 + 1][k2] = __float2half(0.f);
        }
      }
    }
    __syncthreads();

    // phase 2: c = dwconv(K[step-1], u); soft-threshold; mu update; d -> sdm
    bool muZero = (step == 1);
    int ps = step - 1;
#pragma unroll 1
    for (int it = 0; it < 5; ++it) {
      int task = it * 4 + u;
      int o = task / 10, rr = task % 10;
      int y = y0 - 1 + rr;
      int ck = c * 2 + o;
      float4 dq = make_float4(0.f, 0.f, 0.f, 0.f);
      if (y >= 0 && y < HH) {
        const float* Kp = kerK + (ps * CKCH + ck) * 9;
        float kk[9];
#pragma unroll
        for (int q = 0; q < 9; ++q) kk[q] = Kp[q];
        float gm = beta[ps * CKCH + ck] / rho[ps * CKCH + ck];
        float4 c4 = make_float4(0.f, 0.f, 0.f, 0.f);
#pragma unroll
        for (int dy = 0; dy < 3; ++dy) {
          float4 mid = h4tof4(*(const h4*)&S.su[rr + dy][4 + 4 * l]);
          float lft = __shfl_up(mid.w, 1); if (l == 0) lft = 0.f;
          float rgt = __shfl_down(mid.x, 1); if (l == 63) rgt = 0.f;
          float w0 = kk[dy * 3], w1 = kk[dy * 3 + 1], w2 = kk[dy * 3 + 2];
          c4.x += w0 * lft   + w1 * mid.x + w2 * mid.y;
          c4.y += w0 * mid.x + w1 * mid.y + w2 * mid.z;
          c4.z += w0 * mid.y + w1 * mid.z + w2 * mid.w;
          c4.w += w0 * mid.z + w1 * mid.w + w2 * rgt;
        }
        size_t gidx = (((size_t)b * CKCH + ck) * HH + y) * WW + 4 * l;
        float4 m4 = make_float4(0.f, 0.f, 0.f, 0.f);
        if (!muZero) m4 = h4tof4(*(const h4*)(muIn + gidx));
        float4 mn4;
        {
          float v = c4.x + m4.x, av = fabsf(v) - gm;
          float pn = (av > 0.f) ? ((v > 0.f) ? av : -av) : 0.f;
          mn4.x = m4.x + c4.x - pn; dq.x = pn - mn4.x;
        }
        {
          float v = c4.y + m4.y, av = fabsf(v) - gm;
          float pn = (av > 0.f) ? ((v > 0.f) ? av : -av) : 0.f;
          mn4.y = m4.y + c4.y - pn; dq.y = pn - mn4.y;
        }
        {
          float v = c4.z + m4.z, av = fabsf(v) - gm;
          float pn = (av > 0.f) ? ((v > 0.f) ? av : -av) : 0.f;
          mn4.z = m4.z + c4.z - pn; dq.z = pn - mn4.z;
        }
        {
          float v = c4.w + m4.w, av = fabsf(v) - gm;
          float pn = (av > 0.f) ? ((v > 0.f) ? av : -av) : 0.f;
          mn4.w = m4.w + c4.w - pn; dq.w = pn - mn4.w;
        }
        if (rr >= 1 && rr <= 8) *(h4*)(muOut + gidx) = f4toh4(mn4);
      }
      *(h4*)&S.sdm[o][rr][4 + 4 * l] = f4toh4(dq);
    }
  }
  __syncthreads();

  // phase 3: w1 = f + sum_o conv(rho*flipK, d); packed forward row FFT
  int ya = y0 + 2 * u;
  const h4* xa = (const h4*)(xh + ((size_t)(b * CH + c) * HH + ya) * WW);
  float4 va = h4tof4(xa[l]), vb = h4tof4(xa[64 + l]);
  if (!first) {
#pragma unroll
    for (int o = 0; o < 2; ++o) {
      int ck = c * 2 + o;
      float rh = rho[step * CKCH + ck];
      const float* Kk = kerK + (step * CKCH + ck) * 9;
      float kw[9];
#pragma unroll
      for (int dy = 0; dy < 3; ++dy)
#pragma unroll
        for (int dx = 0; dx < 3; ++dx)
          kw[dy * 3 + dx] = rh * Kk[(2 - dy) * 3 + (2 - dx)];
      float4 mid[4]; float lf[4], rg[4];
#pragma unroll
      for (int r4 = 0; r4 < 4; ++r4) {
        mid[r4] = h4tof4(*(const h4*)&S.sdm[o][2 * u + r4][4 + 4 * l]);
        lf[r4] = __shfl_up(mid[r4].w, 1); if (l == 0) lf[r4] = 0.f;
        rg[r4] = __shfl_down(mid[r4].x, 1); if (l == 63) rg[r4] = 0.f;
      }
#pragma unroll
      for (int dy = 0; dy < 3; ++dy) {
        float w0 = kw[dy * 3], w1 = kw[dy * 3 + 1], w2 = kw[dy * 3 + 2];
        va.x += w0 * lf[dy]     + w1 * mid[dy].x   + w2 * mid[dy].y;
        va.y += w0 * mid[dy].x  + w1 * mid[dy].y   + w2 * mid[dy].z;
        va.z += w0 * mid[dy].y  + w1 * mid[dy].z   + w2 * mid[dy].w;
        va.w += w0 * mid[dy].z  + w1 * mid[dy].w   + w2 * rg[dy];
        vb.x += w0 * lf[dy+1]    + w1 * mid[dy+1].x + w2 * mid[dy+1].y;
        vb.y += w0 * mid[dy+1].x + w1 * mid[dy+1].y + w2 * mid[dy+1].z;
        vb.z += w0 * mid[dy+1].y + w1 * mid[dy+1].z + w2 * mid[dy+1].w;
        vb.w += w0 * mid[dy+1].z + w1 * mid[dy+1].w + w2 * rg[dy+1];
      }
    }
  }
  Z[IDX(4 * l + 0)] = make_float2(va.x, vb.x);
  Z[IDX(4 * l + 1)] = make_float2(va.y, vb.y);
  Z[IDX(4 * l + 2)] = make_float2(va.z, vb.z);
  Z[IDX(4 * l + 3)] = make_float2(va.w, vb.w);
  __builtin_amdgcn_wave_barrier();
  wave_fft256<0>(Z, tw, l);
  __half2* Sa = specOut + ((size_t)bc * HH + ya) * SW;
  __half2* Sb = Sa + SW;
#pragma unroll
  for (int h = 0; h < 2; ++h) {
    int k = l + h * 64;
    int mI = (256 - k) & 255;
    float2 zk = Z[IDX(k)], zm = Z[IDX(mI)];
    Sa[k] = __float22half2_rn(make_float2(0.5f * (zk.x + zm.x), 0.5f * (zk.y - zm.y)));
    Sb[k] = __float22half2_rn(make_float2(0.5f * (zk.y + zm.y), 0.5f * (zm.x - zk.x)));
  }
  if (l == 0) {
    float2 z1 = Z[IDX(128)];
    Sa[128] = __float22half2_rn(make_float2(z1.x, 0.f));
    Sb[128] = __float22half2_rn(make_float2(z1.y, 0.f));
  }
}

// ------- colfft: coalesced 8-col tiles, 512 threads, 1 col/wave, group 0 takes kx=128 -------
__global__ __launch_bounds__(512) void fb_colfft(int step, __half2* __restrict__ spec,
                                                 const float* __restrict__ HinvT) {
  int g = blockIdx.x & 15;        // col group: kx 8g..8g+7
  int bc = blockIdx.x >> 4;       // plane (48)
  int c = bc % CH;
  int x0 = g * 8;
  __half2* f = spec + (size_t)bc * HSP;

  __shared__ float2 az[9][257];   // 8 cols (+ kx=128 for g==0); pad 257
  __shared__ float2 tw[128];
  int tid = threadIdx.x;
  if (tid < 128) {
    float sn, cs;
    sincosf(-6.283185307179586f * (float)tid / 256.0f, &sn, &cs);
    tw[tid] = make_float2(cs, sn);
  }
  int col8 = tid & 7;
  int rowq = tid >> 3;            // 0..63
#pragma unroll
  for (int rb = 0; rb < 4; ++rb) {
    int row = rb * 64 + rowq;
    az[col8][IDX(row)] = __half22float2(f[row * SW + x0 + col8]);
  }
  if (g == 0 && tid < 256) az[8][IDX(tid)] = __half22float2(f[tid * SW + 128]);
  __syncthreads();

  int u = tid >> 6, l = tid & 63;
  {
    int kx = x0 + u;
    float2* A = &az[u][0];
    wave_fft256<0>(A, tw, l);
    const float* T = HinvT + ((size_t)(step * CH + c) * 129 + kx) * 256;
#pragma unroll
    for (int h = 0; h < 4; ++h) {
      int idx = l + 64 * h;
      float tv = T[idx];
      float2 z = A[IDX(idx)];
      A[IDX(idx)] = make_float2(z.x * tv, z.y * tv);
    }
    __builtin_amdgcn_wave_barrier();
    wave_fft256<1>(A, tw, l);
  }
  if (g == 0 && u == 0) {         // kx = 128 handled by wave 0
    float2* A = &az[8][0];
    wave_fft256<0>(A, tw, l);
    const float* T = HinvT + ((size_t)(step * CH + c) * 129 + 128) * 256;
#pragma unroll
    for (int h = 0; h < 4; ++h) {
      int idx = l + 64 * h;
      float tv = T[idx];
      float2 z = A[IDX(idx)];
      A[IDX(idx)] = make_float2(z.x * tv, z.y * tv);
    }
    __builtin_amdgcn_wave_barrier();
    wave_fft256<1>(A, tw, l);
  }
  __syncthreads();

#pragma unroll
  for (int rb = 0; rb < 4; ++rb) {
    int row = rb * 64 + rowq;
    f[row * SW + x0 + col8] = __float22half2_rn(az[col8][IDX(row)]);
  }
  if (g == 0 && tid < 256) f[tid * SW + 128] = __float22half2_rn(az[8][IDX(tid)]);
}

// ---------------- final inverse row FFT -> out (fp32) ----------------
__global__ __launch_bounds__(256, 6) void fb_final(const __half2* __restrict__ spec,
                                                   float* __restrict__ out) {
  __shared__ SmBig S;
  __shared__ float2 tw[128];
  int tid = threadIdx.x;
  if (tid < 128) {
    float sn, cs;
    sincosf(-6.283185307179586f * (float)tid / 256.0f, &sn, &cs);
    tw[tid] = make_float2(cs, sn);
  }
  __syncthreads();
  int unit = blockIdx.x;
  int strip = unit & 31;
  int bc = unit >> 5;
  int y0 = strip * 8;
  int u = tid >> 6, l = tid & 63;
  float2* Z = &S.zz[u][0];
  int ya = y0 + 2 * u;
  const __half2* Ar = spec + ((size_t)bc * HH + ya) * SW;
  const __half2* Br = Ar + SW;
#pragma unroll
  for (int h = 0; h < 2; ++h) {
    int t = l + h * 64;
    float2 A = __half22float2(Ar[t]), B = __half22float2(Br[t]);
    Z[IDX(t)] = make_float2(A.x - B.y, A.y + B.x);
    int mI = 128 - t;
    float2 Am = __half22float2(Ar[mI]), Bm = __half22float2(Br[mI]);
    float2 zh;
    if (t == 0) zh = make_float2(Am.x - Bm.y, Am.y + Bm.x);
    else        zh = make_float2(Am.x + Bm.y, Bm.x - Am.y);
    Z[IDX(t + 128)] = zh;
  }
  __builtin_amdgcn_wave_barrier();
  wave_fft256<1>(Z, tw, l);
  float* oa = out + ((size_t)bc * HH + ya) * WW;
#pragma unroll
  for (int h = 0; h < 4; ++h) {
    int xx = l + h * 64;
    float2 z = Z[IDX(xx)];
    oa[xx] = z.x;
    oa[WW + xx] = z.y;
  }
}

extern "C" void kernel_launch(void* const* d_in, const int* in_sizes, int n_in,
                              void* d_out, int out_size, void* d_ws, size_t ws_size,
                              hipStream_t stream) {
  const float4* x4 = (const float4*)d_in[0];
  const float* kerK = (const float*)d_in[1];
  const float* beta = (const float*)d_in[2];
  const float* rho = (const float*)d_in[3];
  float* out = (float*)d_out;

  const size_t PMU = (size_t)BATCH * CKCH * HH * WW;   // 6291456
  const size_t SPL = (size_t)BATCH * CH * HSP;         // 1622016 __half2

  __half* muA = (__half*)d_ws;
  __half* muB = muA + PMU;
  __half2* specA = (__half2*)(muB + PMU);
  __half2* specB = specA + SPL;
  float* HinvT = (float*)(specB + SPL);
  __half* xh = (__half*)(HinvT + (size_t)30 * 129 * 256);

  fb_init<<<NUNITS, 256, 0, stream>>>(x4, xh, kerK, rho, HinvT);
  for (int i = 0; i < NSTEPS; ++i) {
    __half2* sIn = (i & 1) ? specA : specB;
    __half2* sOut = (i & 1) ? specB : specA;
    const __half* mi = (i & 1) ? muB : muA;
    __half* mo = (i & 1) ? muA : muB;
    fb_bigstep<<<NUNITS, 256, 0, stream>>>(i, xh, kerK, beta, rho, sIn, mi, mo, sOut);
    fb_colfft<<<48 * 16, 512, 0, stream>>>(i, sOut, HinvT);
  }
  fb_final<<<NUNITS, 256, 0, stream>>>(specB, out);
}